// Round 7
// baseline (759.220 us; speedup 1.0000x reference)
//
#include <hip/hip_runtime.h>

#define NNODES 50000
#define NBUCK ((NNODES + 63) >> 6)    // 782 buckets of 64 nodes

typedef __attribute__((ext_vector_type(8))) short bf16x8;
typedef __attribute__((ext_vector_type(4))) float f32x4;

__device__ inline short f2bf(float f) {
    unsigned u = __float_as_uint(f);
    unsigned r = (u + 0x7FFFu + ((u >> 16) & 1u)) >> 16;
    return (short)r;
}
__device__ inline float bf2f(short s) {
    return __uint_as_float(((unsigned)(unsigned short)s) << 16);
}
__device__ inline float2 bfp2f(int p) {   // packed pair: low short = elem 0
    float2 f;
    f.x = __uint_as_float((unsigned)p << 16);
    f.y = __uint_as_float((unsigned)p & 0xFFFF0000u);
    return f;
}

// ======================= CSR build: bucketed two-level ======================
// Bucket = 64 consecutive dst nodes. Dense write streams everywhere.
__global__ __launch_bounds__(256) void bucket_count(
    const int* __restrict__ dst, int* __restrict__ bcnt, int E)
{
    __shared__ int h[NBUCK];
    for (int i = threadIdx.x; i < NBUCK; i += 256) h[i] = 0;
    __syncthreads();
    const int stride = gridDim.x * 256;
    for (int e = blockIdx.x * 256 + threadIdx.x; e < E; e += stride)
        atomicAdd(&h[dst[e] >> 6], 1);
    __syncthreads();
    for (int i = threadIdx.x; i < NBUCK; i += 256) {
        int v = h[i];
        if (v) atomicAdd(&bcnt[i], v);
    }
}

__global__ __launch_bounds__(1024) void bucket_scan(
    const int* __restrict__ bcnt, int* __restrict__ bbase, int E)
{
    __shared__ int s[1024];
    int tid = threadIdx.x;
    int v = (tid < NBUCK) ? bcnt[tid] : 0;
    s[tid] = v;
    __syncthreads();
    for (int off = 1; off < 1024; off <<= 1) {
        int t = (tid >= off) ? s[tid - off] : 0;
        __syncthreads();
        s[tid] += t;
        __syncthreads();
    }
    if (tid < NBUCK) bbase[tid] = s[tid] - v;   // exclusive
    if (tid == 0) bbase[NBUCK] = E;
}

// packed edge: (dst & 63) << 16 | src   (src < 65536 since N = 50000)
__global__ __launch_bounds__(256) void bucket_scatter(
    const int* __restrict__ src, const int* __restrict__ dst,
    const int* __restrict__ bbase, int* __restrict__ bpos,
    int* __restrict__ packed, int E)
{
    int e = blockIdx.x * 256 + threadIdx.x;
    if (e < E) {
        int d = dst[e];
        int b = d >> 6;
        int p = atomicAdd(&bpos[b], 1);
        packed[bbase[b] + p] = ((d & 63) << 16) | src[e];
    }
}

// one block per bucket: LDS histogram -> wave scan -> rowptr + dense col fill
__global__ __launch_bounds__(256) void fill_col_bucket(
    const int* __restrict__ bbase, const int* __restrict__ packed,
    int* __restrict__ rowptr, int* __restrict__ col, int N, int E)
{
    __shared__ int hist[64], pos[64], rp[64];
    const int b   = blockIdx.x;
    const int tid = threadIdx.x;
    const int n0  = b << 6;
    const int beg = bbase[b], end = bbase[b + 1];
    if (tid < 64) { hist[tid] = 0; pos[tid] = 0; }
    __syncthreads();
    for (int e = beg + tid; e < end; e += 256)
        atomicAdd(&hist[packed[e] >> 16], 1);
    __syncthreads();
    if (tid < 64) {
        int v = hist[tid];
        int inc = v;
        #pragma unroll
        for (int off = 1; off < 64; off <<= 1) {
            int t = __shfl_up(inc, off, 64);
            if (tid >= off) inc += t;
        }
        int base = beg + inc - v;
        rp[tid] = base;
        if (n0 + tid < N) rowptr[n0 + tid] = base;
        if (b == 0 && tid == 0) rowptr[N] = E;
    }
    __syncthreads();
    for (int e = beg + tid; e < end; e += 256) {
        int pk = packed[e];
        int dl = pk >> 16;
        int p = atomicAdd(&pos[dl], 1);
        col[rp[dl] + p] = pk & 0xFFFF;
    }
}

// ======================= converts ===========================================
__global__ __launch_bounds__(256) void cvt_x(const float* __restrict__ in,
                                             short* __restrict__ out, int n4) {
    int i = blockIdx.x * 256 + threadIdx.x;
    if (i < n4) {
        float4 v = ((const float4*)in)[i];
        short4 s;
        s.x = f2bf(v.x); s.y = f2bf(v.y); s.z = f2bf(v.z); s.w = f2bf(v.w);
        *(short4*)(out + (size_t)i * 4) = s;
    }
}

__global__ __launch_bounds__(256) void cvt_weights(
    const float* __restrict__ p0, const float* __restrict__ p1,
    const float* __restrict__ p2, const float* __restrict__ p3,
    const float* __restrict__ p4, const float* __restrict__ p5,
    const float* __restrict__ p6, const float* __restrict__ p7,
    short* __restrict__ out) {
    int g = blockIdx.x * 256 + threadIdx.x;
    if (g >= 196608) return;
    const float* src; int off;
    if      (g <  32768) { src = p0; off = g; }
    else if (g <  65536) { src = p1; off = g -  32768; }
    else if (g <  81920) { src = p2; off = g -  65536; }
    else if (g <  98304) { src = p3; off = g -  81920; }
    else if (g < 114688) { src = p4; off = g -  98304; }
    else if (g < 131072) { src = p5; off = g - 114688; }
    else if (g < 163840) { src = p6; off = g - 131072; }
    else                 { src = p7; off = g - 163840; }
    out[g] = f2bf(src[off]);
}

// ============ gather-sum over bf16 rows -> bf16 agg (fp32 accumulate) =======
template<int D>
__global__ __launch_bounds__(256) void gather_sum_bf(
    const short* __restrict__ xbf, const int* __restrict__ rowptr,
    const int* __restrict__ col, short* __restrict__ aggbf, int N)
{
    const int wave = threadIdx.x >> 6;
    const int lane = threadIdx.x & 63;
    const int node = blockIdx.x * 4 + wave;
    if (node >= N) return;
    const int beg = rowptr[node], end = rowptr[node + 1];
    int e = beg;
    if (D == 128) {
        float2 acc = make_float2(0.f, 0.f);
        for (; e + 4 <= end; e += 4) {
            int s0 = col[e], s1 = col[e+1], s2 = col[e+2], s3 = col[e+3];
            int p0 = ((const int*)(xbf + (size_t)s0 * D))[lane];
            int p1 = ((const int*)(xbf + (size_t)s1 * D))[lane];
            int p2 = ((const int*)(xbf + (size_t)s2 * D))[lane];
            int p3 = ((const int*)(xbf + (size_t)s3 * D))[lane];
            float2 f0 = bfp2f(p0), f1 = bfp2f(p1), f2 = bfp2f(p2), f3 = bfp2f(p3);
            acc.x += f0.x + f1.x + f2.x + f3.x;
            acc.y += f0.y + f1.y + f2.y + f3.y;
        }
        for (; e < end; e++) {
            float2 f = bfp2f(((const int*)(xbf + (size_t)col[e] * D))[lane]);
            acc.x += f.x; acc.y += f.y;
        }
        short2 s; s.x = f2bf(acc.x); s.y = f2bf(acc.y);
        *(short2*)(aggbf + (size_t)node * D + lane * 2) = s;
    } else {
        float acc = 0.f;
        for (; e + 4 <= end; e += 4) {
            int s0 = col[e], s1 = col[e+1], s2 = col[e+2], s3 = col[e+3];
            acc += bf2f(xbf[(size_t)s0 * D + lane]) + bf2f(xbf[(size_t)s1 * D + lane])
                 + bf2f(xbf[(size_t)s2 * D + lane]) + bf2f(xbf[(size_t)s3 * D + lane]);
        }
        for (; e < end; e++) acc += bf2f(xbf[(size_t)col[e] * D + lane]);
        aggbf[(size_t)node * D + lane] = f2bf(acc);
    }
}

// ==== gather + epilogue: out = lrelu(seg_sum(z[src]) + w + b), zw bf16 ======
template<int D>
__global__ __launch_bounds__(256) void gather_fin(
    const short* __restrict__ zw, const int* __restrict__ rowptr,
    const int* __restrict__ col, const float* __restrict__ bias,
    float* __restrict__ out, short* __restrict__ out_bf, int N)
{
    const int wave = threadIdx.x >> 6;
    const int lane = threadIdx.x & 63;
    const int node = blockIdx.x * 4 + wave;
    if (node >= N) return;
    const int beg = rowptr[node], end = rowptr[node + 1];
    int e = beg;
    if (D == 128) {
        float2 acc = bfp2f(((const int*)(zw + (size_t)node * 256 + 128))[lane]);
        float2 bb = *(const float2*)(bias + lane * 2);
        acc.x += bb.x; acc.y += bb.y;
        for (; e + 4 <= end; e += 4) {
            int s0 = col[e], s1 = col[e+1], s2 = col[e+2], s3 = col[e+3];
            float2 f0 = bfp2f(((const int*)(zw + (size_t)s0 * 256))[lane]);
            float2 f1 = bfp2f(((const int*)(zw + (size_t)s1 * 256))[lane]);
            float2 f2 = bfp2f(((const int*)(zw + (size_t)s2 * 256))[lane]);
            float2 f3 = bfp2f(((const int*)(zw + (size_t)s3 * 256))[lane]);
            acc.x += f0.x + f1.x + f2.x + f3.x;
            acc.y += f0.y + f1.y + f2.y + f3.y;
        }
        for (; e < end; e++) {
            float2 f = bfp2f(((const int*)(zw + (size_t)col[e] * 256))[lane]);
            acc.x += f.x; acc.y += f.y;
        }
        acc.x = acc.x > 0.f ? acc.x : 0.01f * acc.x;
        acc.y = acc.y > 0.f ? acc.y : 0.01f * acc.y;
        *(float2*)(out + (size_t)node * D + lane * 2) = acc;
        if (out_bf) {
            short2 s; s.x = f2bf(acc.x); s.y = f2bf(acc.y);
            *(short2*)(out_bf + (size_t)node * D + lane * 2) = s;
        }
    } else {
        float acc = bf2f(zw[(size_t)node * 128 + 64 + lane]) + bias[lane];
        for (; e + 4 <= end; e += 4) {
            int s0 = col[e], s1 = col[e+1], s2 = col[e+2], s3 = col[e+3];
            acc += bf2f(zw[(size_t)s0 * 128 + lane]) + bf2f(zw[(size_t)s1 * 128 + lane])
                 + bf2f(zw[(size_t)s2 * 128 + lane]) + bf2f(zw[(size_t)s3 * 128 + lane]);
        }
        for (; e < end; e++) acc += bf2f(zw[(size_t)col[e] * 128 + lane]);
        acc = acc > 0.f ? acc : 0.01f * acc;
        out[(size_t)node * D + lane] = acc;
        if (out_bf) out_bf[(size_t)node * D + lane] = f2bf(acc);
    }
}

// ======================= MFMA GEMM (barrier-free K-loop) ====================
template<int DK, int DOUT, bool FUSED>
__global__ __launch_bounds__(256) void gemm_mfma(
    const short* __restrict__ A0, const short* __restrict__ A1,
    const short* __restrict__ B0, const short* __restrict__ B1,
    const float* __restrict__ bias, short* __restrict__ outH, int N)
{
    constexpr int KTOT  = FUSED ? 2 * DK : DK;
    constexpr int NCOLS = FUSED ? DOUT : 2 * DOUT;
    constexpr int K32   = KTOT / 32;
    constexpr int KSEG  = KTOT / 8;
    constexpr int BSH   = 128 * KTOT;
    constexpr int SMSH  = (BSH > 18432) ? BSH : 18432;

    __shared__ short smem[SMSH];
    const int tid  = threadIdx.x;
    const int row0 = blockIdx.x * 128;
    const int col0 = blockIdx.y * 128;
    const int w    = tid >> 6;
    const int lane = tid & 63;
    const int wr   = (w & 1) << 6;
    const int wc   = (w >> 1) << 6;
    const int m16  = lane & 15;
    const int quad = lane >> 4;

    #pragma unroll
    for (int it = 0; it < BSH / 8 / 256; it++) {
        int idx = tid + it * 256;
        int j = idx / KSEG;
        int t = idx % KSEG;
        int gj = col0 + j;
        const short* bp;
        int ko = t * 8;
        if (FUSED) {
            if (ko < DK) bp = B0 + (size_t)gj * DK + ko;
            else         bp = B1 + (size_t)gj * DK + (ko - DK);
        } else {
            bp = (gj < DOUT) ? (B0 + (size_t)gj * DK + ko)
                             : (B1 + (size_t)(gj - DOUT) * DK + ko);
        }
        int4 v = *(const int4*)bp;
        int kk = t >> 2, qd = t & 3, jj = j >> 4, mm = j & 15;
        *(int4*)(smem + ((((jj * K32 + kk) * 4 + qd) * 16 + mm) << 3)) = v;
    }
    __syncthreads();

    const short* arow[4];
    #pragma unroll
    for (int i = 0; i < 4; i++) {
        int r = row0 + wr + i * 16 + m16;
        r = r < N ? r : N - 1;
        arow[i] = A0 + (size_t)r * DK;
    }
    const size_t a1delta = (size_t)(A1 - A0);

    f32x4 acc[4][4] = {};
    const int jw = wc >> 4;

    #pragma unroll
    for (int kk = 0; kk < K32; kk++) {
        const int ko = kk * 32;
        bf16x8 af[4];
        #pragma unroll
        for (int i = 0; i < 4; i++) {
            const short* ap = arow[i] + (quad << 3);
            if (FUSED && ko >= DK) ap += a1delta + (ko - DK);
            else                   ap += ko;
            af[i] = *(const bf16x8*)ap;
        }
        #pragma unroll
        for (int j = 0; j < 4; j++) {
            bf16x8 bfr = *(const bf16x8*)(smem +
                (((((jw + j) * K32 + kk) * 4 + quad) * 16 + m16) << 3));
            #pragma unroll
            for (int i = 0; i < 4; i++)
                acc[i][j] = __builtin_amdgcn_mfma_f32_16x16x32_bf16(
                    af[i], bfr, acc[i][j], 0, 0, 0);
        }
    }

    __syncthreads();
    short* ep = smem + w * 4608;
    #pragma unroll
    for (int j = 0; j < 4; j++) {
        const int colg = col0 + wc + j * 16 + m16;
        const float bv = FUSED ? bias[colg] : 0.f;
        #pragma unroll
        for (int i = 0; i < 4; i++) {
            #pragma unroll
            for (int r = 0; r < 4; r++) {
                float v = acc[i][j][r];
                if (FUSED) { v += bv; v = v > 0.f ? v : 0.01f * v; }
                ep[(i * 16 + quad * 4 + r) * 72 + j * 16 + m16] = f2bf(v);
            }
        }
    }
    const int r8  = lane >> 3;
    const int seg = lane & 7;
    #pragma unroll
    for (int rb = 0; rb < 8; rb++) {
        const int lrow = rb * 8 + r8;
        int4 vv = *(const int4*)(ep + lrow * 72 + seg * 8);
        const int grow = row0 + wr + lrow;
        if (grow < N)
            *(int4*)(outH + (size_t)grow * NCOLS + col0 + wc + seg * 8) = vv;
    }
}

extern "C" void kernel_launch(void* const* d_in, const int* in_sizes, int n_in,
                              void* d_out, int out_size, void* d_ws, size_t ws_size,
                              hipStream_t stream) {
    const int N = NNODES;
    const float* x  = (const float*)d_in[0];
    const int*   ei = (const int*)d_in[1];
    const int    E  = in_sizes[1] / 2;
    const int* src = ei;
    const int* dst = ei + E;

    const float* Wr[4] = { (const float*)d_in[2], (const float*)d_in[5],
                           (const float*)d_in[8], (const float*)d_in[11] };
    const float* Ws[4] = { (const float*)d_in[3], (const float*)d_in[6],
                           (const float*)d_in[9], (const float*)d_in[12] };
    const float* bb[4] = { (const float*)d_in[4], (const float*)d_in[7],
                           (const float*)d_in[10], (const float*)d_in[13] };

    float* out  = (float*)d_out;                     // h_final: N x 128 fp32
    float* emb  = out + (size_t)N * 128;             // emb:     N x 64 fp32

    // workspace layout
    short* zwbf   = (short*)d_ws;                    // N x 256 bf16 (z|w)
    short* aggbf  = zwbf + (size_t)N * 256;          // N x 128 bf16
    short* xbf    = aggbf + (size_t)N * 128;         // N x 128 bf16
    short* h1bf   = xbf + (size_t)N * 128;           // N x 256 bf16 (also h3)
    short* embbf  = h1bf + (size_t)N * 256;          // N x 64 bf16
    short* wbf    = embbf + (size_t)N * 64;          // 196608 bf16 weights
    int*   rowptr = (int*)(wbf + 196608);            // N+1
    int*   col    = rowptr + (N + 1);                // E
    int*   packed = col + E;                         // E
    int*   bcnt   = packed + E;                      // NBUCK
    int*   bpos   = bcnt + NBUCK;                    // NBUCK
    int*   bbase  = bpos + NBUCK;                    // NBUCK+1

    const short* wr0 = wbf;           const short* ws0 = wbf + 32768;
    const short* wr1 = wbf + 65536;   const short* ws1 = wbf + 81920;
    const short* wr2 = wbf + 98304;   const short* ws2 = wbf + 114688;
    const short* wr3 = wbf + 131072;  const short* ws3 = wbf + 163840;

    const int eb = (E + 255) / 256;
    const int gemmRB = (N + 127) / 128;              // 391
    const int nodeBlocks = (N + 3) / 4;

    // ---- CSR build (bucketed) + converts ----
    hipMemsetAsync(bcnt, 0, 2 * NBUCK * sizeof(int), stream);   // bcnt + bpos
    bucket_count<<<256, 256, 0, stream>>>(dst, bcnt, E);
    bucket_scan<<<1, 1024, 0, stream>>>(bcnt, bbase, E);
    bucket_scatter<<<eb, 256, 0, stream>>>(src, dst, bbase, bpos, packed, E);
    fill_col_bucket<<<NBUCK, 256, 0, stream>>>(bbase, packed, rowptr, col, N, E);
    cvt_x<<<(N * 128 / 4 + 255) / 256, 256, 0, stream>>>(x, xbf, N * 128 / 4);
    cvt_weights<<<(196608 + 255) / 256, 256, 0, stream>>>(
        Wr[0], Ws[0], Wr[1], Ws[1], Wr[2], Ws[2], Wr[3], Ws[3], wbf);

    // ---- Layer 0 (gather-first): 128 -> 256 ----
    gather_sum_bf<128><<<nodeBlocks, 256, 0, stream>>>(xbf, rowptr, col, aggbf, N);
    gemm_mfma<128, 256, true><<<dim3(gemmRB, 2), 256, 0, stream>>>(
        aggbf, xbf, wr0, ws0, bb[0], h1bf, N);

    // ---- Layer 1 (GEMM-first): 256 -> 64 ----
    gemm_mfma<256, 64, false><<<dim3(gemmRB, 1), 256, 0, stream>>>(
        h1bf, nullptr, wr1, ws1, nullptr, zwbf, N);            // zw1: N x 128
    gather_fin<64><<<nodeBlocks, 256, 0, stream>>>(
        zwbf, rowptr, col, bb[1], emb, embbf, N);

    // ---- Layer 2 (gather-first): 64 -> 256 ----
    gather_sum_bf<64><<<nodeBlocks, 256, 0, stream>>>(embbf, rowptr, col, aggbf, N);
    gemm_mfma<64, 256, true><<<dim3(gemmRB, 2), 256, 0, stream>>>(
        aggbf, embbf, wr2, ws2, bb[2], h1bf /*h3bf*/, N);

    // ---- Layer 3 (GEMM-first): 256 -> 128 ----
    gemm_mfma<256, 128, false><<<dim3(gemmRB, 2), 256, 0, stream>>>(
        h1bf /*h3bf*/, nullptr, wr3, ws3, nullptr, zwbf, N);   // zw3: N x 256
    gather_fin<128><<<nodeBlocks, 256, 0, stream>>>(
        zwbf, rowptr, col, bb[3], out, nullptr, N);
}

// Round 8
// 360.781 us; speedup vs baseline: 2.1044x; 2.1044x over previous
//
#include <hip/hip_runtime.h>

#define NNODES 50000
#define NCB 196                       // coarse buckets of 256 nodes

typedef __attribute__((ext_vector_type(8))) short bf16x8;
typedef __attribute__((ext_vector_type(4))) float f32x4;

__device__ inline short f2bf(float f) {
    unsigned u = __float_as_uint(f);
    unsigned r = (u + 0x7FFFu + ((u >> 16) & 1u)) >> 16;
    return (short)r;
}
__device__ inline float bf2f(short s) {
    return __uint_as_float(((unsigned)(unsigned short)s) << 16);
}
__device__ inline float2 bfp2f(int p) {   // packed pair: low short = elem 0
    float2 f;
    f.x = __uint_as_float((unsigned)p << 16);
    f.y = __uint_as_float((unsigned)p & 0xFFFF0000u);
    return f;
}

// 256-thread exclusive scan (uses lds[0..4]); includes barriers.
__device__ inline int excl_scan_256(int v, int* lds, int tid) {
    int lane = tid & 63, w = tid >> 6;
    int incl = v;
    #pragma unroll
    for (int off = 1; off < 64; off <<= 1) {
        int t = __shfl_up(incl, off, 64);
        if (lane >= off) incl += t;
    }
    if (lane == 63) lds[w] = incl;
    __syncthreads();
    if (tid == 0) {
        int s = 0;
        #pragma unroll
        for (int i = 0; i < 4; i++) { int t = lds[i]; lds[i] = s; s += t; }
    }
    __syncthreads();
    return incl - v + lds[w];
}

// ============== CSR build: contention-free counting sort ====================
// Pass 1: per-chunk histogram over 196 coarse buckets.
__global__ __launch_bounds__(256) void hist_coarse(
    const int* __restrict__ dst, int* __restrict__ histG, int E, int chunk)
{
    __shared__ int h[NCB];
    const int tid = threadIdx.x;
    for (int i = tid; i < NCB; i += 256) h[i] = 0;
    __syncthreads();
    const int beg = blockIdx.x * chunk;
    const int end = min(beg + chunk, E);
    for (int e = beg + tid; e < end; e += 256)
        atomicAdd(&h[dst[e] >> 8], 1);
    __syncthreads();
    for (int i = tid; i < NCB; i += 256)
        histG[i * 256 + blockIdx.x] = h[i];
}

// Pass 2a: per-bucket exclusive scan over its 256 chunk-counts (in place).
__global__ __launch_bounds__(256) void scan_buckets(
    int* __restrict__ histG, int* __restrict__ btot)
{
    __shared__ int lds[8];
    const int tid = threadIdx.x;
    const int b = blockIdx.x;
    int v = histG[b * 256 + tid];
    int ex = excl_scan_256(v, lds, tid);
    histG[b * 256 + tid] = ex;
    if (tid == 255) btot[b] = ex + v;
}

// Pass 2b: scan 196 bucket totals -> bases[197].
__global__ __launch_bounds__(256) void scan_bases(
    const int* __restrict__ btot, int* __restrict__ bases, int E)
{
    __shared__ int lds[8];
    const int tid = threadIdx.x;
    int v = (tid < NCB) ? btot[tid] : 0;
    int ex = excl_scan_256(v, lds, tid);
    if (tid <= NCB) bases[tid] = ex;   // bases[NCB] == E
}

// Pass 3: scatter packed edges into coarse order. LDS counters only.
__global__ __launch_bounds__(256) void scatter_coarse(
    const int* __restrict__ src, const int* __restrict__ dst,
    const int* __restrict__ histG, const int* __restrict__ bases,
    int* __restrict__ coarse, int E, int chunk)
{
    __shared__ int pos[NCB];
    const int tid = threadIdx.x;
    const int blk = blockIdx.x;
    for (int i = tid; i < NCB; i += 256)
        pos[i] = bases[i] + histG[i * 256 + blk];
    __syncthreads();
    const int beg = blk * chunk;
    const int end = min(beg + chunk, E);
    for (int e = beg + tid; e < end; e += 256) {
        int d = dst[e];
        int p = atomicAdd(&pos[d >> 8], 1);
        coarse[p] = ((d & 255) << 16) | src[e];
    }
}

// Pass 4: per-bucket local histogram + scan -> rowptr + dense col fill.
__global__ __launch_bounds__(256) void fill_from_coarse(
    const int* __restrict__ bases, const int* __restrict__ coarse,
    int* __restrict__ rowptr, int* __restrict__ col, int N)
{
    __shared__ int hist[256], rp[256], pos[256];
    __shared__ int lds[8];
    const int cb  = blockIdx.x;
    const int tid = threadIdx.x;
    const int n0  = cb << 8;
    const int beg = bases[cb], end = bases[cb + 1];
    hist[tid] = 0; pos[tid] = 0;
    __syncthreads();
    for (int e = beg + tid; e < end; e += 256)
        atomicAdd(&hist[coarse[e] >> 16], 1);
    __syncthreads();
    int ex = excl_scan_256(hist[tid], lds, tid);
    rp[tid] = beg + ex;
    if (n0 + tid <= N) rowptr[n0 + tid] = beg + ex;
    __syncthreads();
    for (int e = beg + tid; e < end; e += 256) {
        int pk = coarse[e];
        int dl = pk >> 16;
        int p = atomicAdd(&pos[dl], 1);
        col[rp[dl] + p] = pk & 0xFFFF;
    }
}

// ======================= converts ===========================================
__global__ __launch_bounds__(256) void cvt_x(const float* __restrict__ in,
                                             short* __restrict__ out, int n4) {
    int i = blockIdx.x * 256 + threadIdx.x;
    if (i < n4) {
        float4 v = ((const float4*)in)[i];
        short4 s;
        s.x = f2bf(v.x); s.y = f2bf(v.y); s.z = f2bf(v.z); s.w = f2bf(v.w);
        *(short4*)(out + (size_t)i * 4) = s;
    }
}

__global__ __launch_bounds__(256) void cvt_weights(
    const float* __restrict__ p0, const float* __restrict__ p1,
    const float* __restrict__ p2, const float* __restrict__ p3,
    const float* __restrict__ p4, const float* __restrict__ p5,
    const float* __restrict__ p6, const float* __restrict__ p7,
    short* __restrict__ out) {
    int g = blockIdx.x * 256 + threadIdx.x;
    if (g >= 196608) return;
    const float* src; int off;
    if      (g <  32768) { src = p0; off = g; }
    else if (g <  65536) { src = p1; off = g -  32768; }
    else if (g <  81920) { src = p2; off = g -  65536; }
    else if (g <  98304) { src = p3; off = g -  81920; }
    else if (g < 114688) { src = p4; off = g -  98304; }
    else if (g < 131072) { src = p5; off = g - 114688; }
    else if (g < 163840) { src = p6; off = g - 131072; }
    else                 { src = p7; off = g - 163840; }
    out[g] = f2bf(src[off]);
}

// ============ gather-sum over bf16 rows -> bf16 agg (fp32 accumulate) =======
template<int D>
__global__ __launch_bounds__(256) void gather_sum_bf(
    const short* __restrict__ xbf, const int* __restrict__ rowptr,
    const int* __restrict__ col, short* __restrict__ aggbf, int N)
{
    const int wave = threadIdx.x >> 6;
    const int lane = threadIdx.x & 63;
    const int node = blockIdx.x * 4 + wave;
    if (node >= N) return;
    const int beg = rowptr[node], end = rowptr[node + 1];
    int e = beg;
    if (D == 128) {
        float2 acc = make_float2(0.f, 0.f);
        for (; e + 4 <= end; e += 4) {
            int s0 = col[e], s1 = col[e+1], s2 = col[e+2], s3 = col[e+3];
            int p0 = ((const int*)(xbf + (size_t)s0 * D))[lane];
            int p1 = ((const int*)(xbf + (size_t)s1 * D))[lane];
            int p2 = ((const int*)(xbf + (size_t)s2 * D))[lane];
            int p3 = ((const int*)(xbf + (size_t)s3 * D))[lane];
            float2 f0 = bfp2f(p0), f1 = bfp2f(p1), f2 = bfp2f(p2), f3 = bfp2f(p3);
            acc.x += f0.x + f1.x + f2.x + f3.x;
            acc.y += f0.y + f1.y + f2.y + f3.y;
        }
        for (; e < end; e++) {
            float2 f = bfp2f(((const int*)(xbf + (size_t)col[e] * D))[lane]);
            acc.x += f.x; acc.y += f.y;
        }
        short2 s; s.x = f2bf(acc.x); s.y = f2bf(acc.y);
        *(short2*)(aggbf + (size_t)node * D + lane * 2) = s;
    } else {
        float acc = 0.f;
        for (; e + 4 <= end; e += 4) {
            int s0 = col[e], s1 = col[e+1], s2 = col[e+2], s3 = col[e+3];
            acc += bf2f(xbf[(size_t)s0 * D + lane]) + bf2f(xbf[(size_t)s1 * D + lane])
                 + bf2f(xbf[(size_t)s2 * D + lane]) + bf2f(xbf[(size_t)s3 * D + lane]);
        }
        for (; e < end; e++) acc += bf2f(xbf[(size_t)col[e] * D + lane]);
        aggbf[(size_t)node * D + lane] = f2bf(acc);
    }
}

// ==== gather + epilogue: out = lrelu(seg_sum(z[src]) + w + b), zw bf16 ======
template<int D>
__global__ __launch_bounds__(256) void gather_fin(
    const short* __restrict__ zw, const int* __restrict__ rowptr,
    const int* __restrict__ col, const float* __restrict__ bias,
    float* __restrict__ out, short* __restrict__ out_bf, int N)
{
    const int wave = threadIdx.x >> 6;
    const int lane = threadIdx.x & 63;
    const int node = blockIdx.x * 4 + wave;
    if (node >= N) return;
    const int beg = rowptr[node], end = rowptr[node + 1];
    int e = beg;
    if (D == 128) {
        float2 acc = bfp2f(((const int*)(zw + (size_t)node * 256 + 128))[lane]);
        float2 bb = *(const float2*)(bias + lane * 2);
        acc.x += bb.x; acc.y += bb.y;
        for (; e + 4 <= end; e += 4) {
            int s0 = col[e], s1 = col[e+1], s2 = col[e+2], s3 = col[e+3];
            float2 f0 = bfp2f(((const int*)(zw + (size_t)s0 * 256))[lane]);
            float2 f1 = bfp2f(((const int*)(zw + (size_t)s1 * 256))[lane]);
            float2 f2 = bfp2f(((const int*)(zw + (size_t)s2 * 256))[lane]);
            float2 f3 = bfp2f(((const int*)(zw + (size_t)s3 * 256))[lane]);
            acc.x += f0.x + f1.x + f2.x + f3.x;
            acc.y += f0.y + f1.y + f2.y + f3.y;
        }
        for (; e < end; e++) {
            float2 f = bfp2f(((const int*)(zw + (size_t)col[e] * 256))[lane]);
            acc.x += f.x; acc.y += f.y;
        }
        acc.x = acc.x > 0.f ? acc.x : 0.01f * acc.x;
        acc.y = acc.y > 0.f ? acc.y : 0.01f * acc.y;
        *(float2*)(out + (size_t)node * D + lane * 2) = acc;
        if (out_bf) {
            short2 s; s.x = f2bf(acc.x); s.y = f2bf(acc.y);
            *(short2*)(out_bf + (size_t)node * D + lane * 2) = s;
        }
    } else {
        float acc = bf2f(zw[(size_t)node * 128 + 64 + lane]) + bias[lane];
        for (; e + 4 <= end; e += 4) {
            int s0 = col[e], s1 = col[e+1], s2 = col[e+2], s3 = col[e+3];
            acc += bf2f(zw[(size_t)s0 * 128 + lane]) + bf2f(zw[(size_t)s1 * 128 + lane])
                 + bf2f(zw[(size_t)s2 * 128 + lane]) + bf2f(zw[(size_t)s3 * 128 + lane]);
        }
        for (; e < end; e++) acc += bf2f(zw[(size_t)col[e] * 128 + lane]);
        acc = acc > 0.f ? acc : 0.01f * acc;
        out[(size_t)node * D + lane] = acc;
        if (out_bf) out_bf[(size_t)node * D + lane] = f2bf(acc);
    }
}

// ======================= MFMA GEMM (barrier-free K-loop) ====================
template<int DK, int DOUT, bool FUSED>
__global__ __launch_bounds__(256) void gemm_mfma(
    const short* __restrict__ A0, const short* __restrict__ A1,
    const short* __restrict__ B0, const short* __restrict__ B1,
    const float* __restrict__ bias, short* __restrict__ outH, int N)
{
    constexpr int KTOT  = FUSED ? 2 * DK : DK;
    constexpr int NCOLS = FUSED ? DOUT : 2 * DOUT;
    constexpr int K32   = KTOT / 32;
    constexpr int KSEG  = KTOT / 8;
    constexpr int BSH   = 128 * KTOT;
    constexpr int SMSH  = (BSH > 18432) ? BSH : 18432;

    __shared__ short smem[SMSH];
    const int tid  = threadIdx.x;
    const int row0 = blockIdx.x * 128;
    const int col0 = blockIdx.y * 128;
    const int w    = tid >> 6;
    const int lane = tid & 63;
    const int wr   = (w & 1) << 6;
    const int wc   = (w >> 1) << 6;
    const int m16  = lane & 15;
    const int quad = lane >> 4;

    #pragma unroll
    for (int it = 0; it < BSH / 8 / 256; it++) {
        int idx = tid + it * 256;
        int j = idx / KSEG;
        int t = idx % KSEG;
        int gj = col0 + j;
        const short* bp;
        int ko = t * 8;
        if (FUSED) {
            if (ko < DK) bp = B0 + (size_t)gj * DK + ko;
            else         bp = B1 + (size_t)gj * DK + (ko - DK);
        } else {
            bp = (gj < DOUT) ? (B0 + (size_t)gj * DK + ko)
                             : (B1 + (size_t)(gj - DOUT) * DK + ko);
        }
        int4 v = *(const int4*)bp;
        int kk = t >> 2, qd = t & 3, jj = j >> 4, mm = j & 15;
        *(int4*)(smem + ((((jj * K32 + kk) * 4 + qd) * 16 + mm) << 3)) = v;
    }
    __syncthreads();

    const short* arow[4];
    #pragma unroll
    for (int i = 0; i < 4; i++) {
        int r = row0 + wr + i * 16 + m16;
        r = r < N ? r : N - 1;
        arow[i] = A0 + (size_t)r * DK;
    }
    const size_t a1delta = (size_t)(A1 - A0);

    f32x4 acc[4][4] = {};
    const int jw = wc >> 4;

    #pragma unroll
    for (int kk = 0; kk < K32; kk++) {
        const int ko = kk * 32;
        bf16x8 af[4];
        #pragma unroll
        for (int i = 0; i < 4; i++) {
            const short* ap = arow[i] + (quad << 3);
            if (FUSED && ko >= DK) ap += a1delta + (ko - DK);
            else                   ap += ko;
            af[i] = *(const bf16x8*)ap;
        }
        #pragma unroll
        for (int j = 0; j < 4; j++) {
            bf16x8 bfr = *(const bf16x8*)(smem +
                (((((jw + j) * K32 + kk) * 4 + quad) * 16 + m16) << 3));
            #pragma unroll
            for (int i = 0; i < 4; i++)
                acc[i][j] = __builtin_amdgcn_mfma_f32_16x16x32_bf16(
                    af[i], bfr, acc[i][j], 0, 0, 0);
        }
    }

    __syncthreads();
    short* ep = smem + w * 4608;
    #pragma unroll
    for (int j = 0; j < 4; j++) {
        const int colg = col0 + wc + j * 16 + m16;
        const float bv = FUSED ? bias[colg] : 0.f;
        #pragma unroll
        for (int i = 0; i < 4; i++) {
            #pragma unroll
            for (int r = 0; r < 4; r++) {
                float v = acc[i][j][r];
                if (FUSED) { v += bv; v = v > 0.f ? v : 0.01f * v; }
                ep[(i * 16 + quad * 4 + r) * 72 + j * 16 + m16] = f2bf(v);
            }
        }
    }
    const int r8  = lane >> 3;
    const int seg = lane & 7;
    #pragma unroll
    for (int rb = 0; rb < 8; rb++) {
        const int lrow = rb * 8 + r8;
        int4 vv = *(const int4*)(ep + lrow * 72 + seg * 8);
        const int grow = row0 + wr + lrow;
        if (grow < N)
            *(int4*)(outH + (size_t)grow * NCOLS + col0 + wc + seg * 8) = vv;
    }
}

extern "C" void kernel_launch(void* const* d_in, const int* in_sizes, int n_in,
                              void* d_out, int out_size, void* d_ws, size_t ws_size,
                              hipStream_t stream) {
    const int N = NNODES;
    const float* x  = (const float*)d_in[0];
    const int*   ei = (const int*)d_in[1];
    const int    E  = in_sizes[1] / 2;
    const int* src = ei;
    const int* dst = ei + E;

    const float* Wr[4] = { (const float*)d_in[2], (const float*)d_in[5],
                           (const float*)d_in[8], (const float*)d_in[11] };
    const float* Ws[4] = { (const float*)d_in[3], (const float*)d_in[6],
                           (const float*)d_in[9], (const float*)d_in[12] };
    const float* bb[4] = { (const float*)d_in[4], (const float*)d_in[7],
                           (const float*)d_in[10], (const float*)d_in[13] };

    float* out  = (float*)d_out;                     // h_final: N x 128 fp32
    float* emb  = out + (size_t)N * 128;             // emb:     N x 64 fp32

    // workspace layout
    short* zwbf   = (short*)d_ws;                    // N x 256 bf16 (z|w)
    short* aggbf  = zwbf + (size_t)N * 256;          // N x 128 bf16
    short* xbf    = aggbf + (size_t)N * 128;         // N x 128 bf16
    short* h1bf   = xbf + (size_t)N * 128;           // N x 256 bf16 (also h3)
    short* embbf  = h1bf + (size_t)N * 256;          // N x 64 bf16
    short* wbf    = embbf + (size_t)N * 64;          // 196608 bf16 weights
    int*   rowptr = (int*)(wbf + 196608);            // N+1
    int*   col    = rowptr + (N + 1);                // E
    int*   coarse = col + E;                         // E
    int*   histG  = coarse + E;                      // NCB*256
    int*   btot   = histG + NCB * 256;               // NCB
    int*   bases  = btot + NCB;                      // NCB+1

    const short* wr0 = wbf;           const short* ws0 = wbf + 32768;
    const short* wr1 = wbf + 65536;   const short* ws1 = wbf + 81920;
    const short* wr2 = wbf + 98304;   const short* ws2 = wbf + 114688;
    const short* wr3 = wbf + 131072;  const short* ws3 = wbf + 163840;

    const int chunk = (E + 255) / 256;
    const int gemmRB = (N + 127) / 128;              // 391
    const int nodeBlocks = (N + 3) / 4;

    // ---- CSR build (contention-free counting sort) + converts ----
    hist_coarse<<<256, 256, 0, stream>>>(dst, histG, E, chunk);
    scan_buckets<<<NCB, 256, 0, stream>>>(histG, btot);
    scan_bases<<<1, 256, 0, stream>>>(btot, bases, E);
    scatter_coarse<<<256, 256, 0, stream>>>(src, dst, histG, bases, coarse, E, chunk);
    fill_from_coarse<<<NCB, 256, 0, stream>>>(bases, coarse, rowptr, col, N);
    cvt_x<<<(N * 128 / 4 + 255) / 256, 256, 0, stream>>>(x, xbf, N * 128 / 4);
    cvt_weights<<<(196608 + 255) / 256, 256, 0, stream>>>(
        Wr[0], Ws[0], Wr[1], Ws[1], Wr[2], Ws[2], Wr[3], Ws[3], wbf);

    // ---- Layer 0 (gather-first): 128 -> 256 ----
    gather_sum_bf<128><<<nodeBlocks, 256, 0, stream>>>(xbf, rowptr, col, aggbf, N);
    gemm_mfma<128, 256, true><<<dim3(gemmRB, 2), 256, 0, stream>>>(
        aggbf, xbf, wr0, ws0, bb[0], h1bf, N);

    // ---- Layer 1 (GEMM-first): 256 -> 64 ----
    gemm_mfma<256, 64, false><<<dim3(gemmRB, 1), 256, 0, stream>>>(
        h1bf, nullptr, wr1, ws1, nullptr, zwbf, N);            // zw1: N x 128
    gather_fin<64><<<nodeBlocks, 256, 0, stream>>>(
        zwbf, rowptr, col, bb[1], emb, embbf, N);

    // ---- Layer 2 (gather-first): 64 -> 256 ----
    gather_sum_bf<64><<<nodeBlocks, 256, 0, stream>>>(embbf, rowptr, col, aggbf, N);
    gemm_mfma<64, 256, true><<<dim3(gemmRB, 2), 256, 0, stream>>>(
        aggbf, embbf, wr2, ws2, bb[2], h1bf /*h3bf*/, N);

    // ---- Layer 3 (GEMM-first): 256 -> 128 ----
    gemm_mfma<256, 128, false><<<dim3(gemmRB, 2), 256, 0, stream>>>(
        h1bf /*h3bf*/, nullptr, wr3, ws3, nullptr, zwbf, N);   // zw3: N x 256
    gather_fin<128><<<nodeBlocks, 256, 0, stream>>>(
        zwbf, rowptr, col, bb[3], out, nullptr, N);
}

// Round 10
// 347.426 us; speedup vs baseline: 2.1853x; 1.0384x over previous
//
#include <hip/hip_runtime.h>

#define NNODES 50000
#define NCB 196                       // coarse buckets of 256 nodes

typedef __attribute__((ext_vector_type(8))) short bf16x8;
typedef __attribute__((ext_vector_type(4))) float f32x4;

__device__ inline short f2bf(float f) {
    unsigned u = __float_as_uint(f);
    unsigned r = (u + 0x7FFFu + ((u >> 16) & 1u)) >> 16;
    return (short)r;
}
__device__ inline float bf2f(short s) {
    return __uint_as_float(((unsigned)(unsigned short)s) << 16);
}
__device__ inline float2 bfp2f(int p) {   // packed pair: low short = elem 0
    float2 f;
    f.x = __uint_as_float((unsigned)p << 16);
    f.y = __uint_as_float((unsigned)p & 0xFFFF0000u);
    return f;
}
__device__ inline void addbf4(float4& a, int2 v) {
    float2 lo = bfp2f(v.x), hi = bfp2f(v.y);
    a.x += lo.x; a.y += lo.y; a.z += hi.x; a.w += hi.y;
}

// 256-thread exclusive scan (uses lds[0..4]); includes barriers.
__device__ inline int excl_scan_256(int v, int* lds, int tid) {
    int lane = tid & 63, w = tid >> 6;
    int incl = v;
    #pragma unroll
    for (int off = 1; off < 64; off <<= 1) {
        int t = __shfl_up(incl, off, 64);
        if (lane >= off) incl += t;
    }
    if (lane == 63) lds[w] = incl;
    __syncthreads();
    if (tid == 0) {
        int s = 0;
        #pragma unroll
        for (int i = 0; i < 4; i++) { int t = lds[i]; lds[i] = s; s += t; }
    }
    __syncthreads();
    return incl - v + lds[w];
}

// ============== CSR build: contention-free counting sort ====================
__global__ __launch_bounds__(256) void hist_coarse(
    const int* __restrict__ dst, int* __restrict__ histG, int E, int chunk)
{
    __shared__ int h[NCB];
    const int tid = threadIdx.x;
    for (int i = tid; i < NCB; i += 256) h[i] = 0;
    __syncthreads();
    const int beg = blockIdx.x * chunk;
    const int end = min(beg + chunk, E);
    for (int e = beg + tid; e < end; e += 256)
        atomicAdd(&h[dst[e] >> 8], 1);
    __syncthreads();
    for (int i = tid; i < NCB; i += 256)
        histG[i * 256 + blockIdx.x] = h[i];
}

__global__ __launch_bounds__(256) void scan_buckets(
    int* __restrict__ histG, int* __restrict__ btot)
{
    __shared__ int lds[8];
    const int tid = threadIdx.x;
    const int b = blockIdx.x;
    int v = histG[b * 256 + tid];
    int ex = excl_scan_256(v, lds, tid);
    histG[b * 256 + tid] = ex;
    if (tid == 255) btot[b] = ex + v;
}

__global__ __launch_bounds__(256) void scan_bases(
    const int* __restrict__ btot, int* __restrict__ bases, int E)
{
    __shared__ int lds[8];
    const int tid = threadIdx.x;
    int v = (tid < NCB) ? btot[tid] : 0;
    int ex = excl_scan_256(v, lds, tid);
    if (tid <= NCB) bases[tid] = ex;   // bases[NCB] == E
}

__global__ __launch_bounds__(256) void scatter_coarse(
    const int* __restrict__ src, const int* __restrict__ dst,
    const int* __restrict__ histG, const int* __restrict__ bases,
    int* __restrict__ coarse, int E, int chunk)
{
    __shared__ int pos[NCB];
    const int tid = threadIdx.x;
    const int blk = blockIdx.x;
    for (int i = tid; i < NCB; i += 256)
        pos[i] = bases[i] + histG[i * 256 + blk];
    __syncthreads();
    const int beg = blk * chunk;
    const int end = min(beg + chunk, E);
    for (int e = beg + tid; e < end; e += 256) {
        int d = dst[e];
        int p = atomicAdd(&pos[d >> 8], 1);
        coarse[p] = ((d & 255) << 16) | src[e];
    }
}

__global__ __launch_bounds__(256) void fill_from_coarse(
    const int* __restrict__ bases, const int* __restrict__ coarse,
    int* __restrict__ rowptr, int* __restrict__ col, int N)
{
    __shared__ int hist[256], rp[256], pos[256];
    __shared__ int lds[8];
    const int cb  = blockIdx.x;
    const int tid = threadIdx.x;
    const int n0  = cb << 8;
    const int beg = bases[cb], end = bases[cb + 1];
    hist[tid] = 0; pos[tid] = 0;
    __syncthreads();
    for (int e = beg + tid; e < end; e += 256)
        atomicAdd(&hist[coarse[e] >> 16], 1);
    __syncthreads();
    int ex = excl_scan_256(hist[tid], lds, tid);
    rp[tid] = beg + ex;
    if (n0 + tid <= N) rowptr[n0 + tid] = beg + ex;
    __syncthreads();
    for (int e = beg + tid; e < end; e += 256) {
        int pk = coarse[e];
        int dl = pk >> 16;
        int p = atomicAdd(&pos[dl], 1);
        col[rp[dl] + p] = pk & 0xFFFF;
    }
}

// ======================= converts ===========================================
__global__ __launch_bounds__(256) void cvt_x(const float* __restrict__ in,
                                             short* __restrict__ out, int n4) {
    int i = blockIdx.x * 256 + threadIdx.x;
    if (i < n4) {
        float4 v = ((const float4*)in)[i];
        short4 s;
        s.x = f2bf(v.x); s.y = f2bf(v.y); s.z = f2bf(v.z); s.w = f2bf(v.w);
        *(short4*)(out + (size_t)i * 4) = s;
    }
}

__global__ __launch_bounds__(256) void cvt_weights(
    const float* __restrict__ p0, const float* __restrict__ p1,
    const float* __restrict__ p2, const float* __restrict__ p3,
    const float* __restrict__ p4, const float* __restrict__ p5,
    const float* __restrict__ p6, const float* __restrict__ p7,
    short* __restrict__ out) {
    int g = blockIdx.x * 256 + threadIdx.x;
    if (g >= 196608) return;
    const float* src; int off;
    if      (g <  32768) { src = p0; off = g; }
    else if (g <  65536) { src = p1; off = g -  32768; }
    else if (g <  81920) { src = p2; off = g -  65536; }
    else if (g <  98304) { src = p3; off = g -  81920; }
    else if (g < 114688) { src = p4; off = g -  98304; }
    else if (g < 131072) { src = p5; off = g - 114688; }
    else if (g < 163840) { src = p6; off = g - 131072; }
    else                 { src = p7; off = g - 163840; }
    out[g] = f2bf(src[off]);
}

// ====== gather-sum, multi-edge-per-wave (bf16 rows, fp32 accumulate) ========
// D=128: 2 groups x 32 lanes, 2 edges/issue. One wave per node.
__global__ __launch_bounds__(256) void gather_sum128(
    const short* __restrict__ xbf, const int* __restrict__ rowptr,
    const int* __restrict__ col, short* __restrict__ aggbf, int N)
{
    const int wave = threadIdx.x >> 6;
    const int lane = threadIdx.x & 63;
    const int node = blockIdx.x * 4 + wave;
    if (node >= N) return;
    const int g = lane >> 5;          // edge group 0..1
    const int c = lane & 31;          // int2 slot within row (4 shorts)
    const int beg = rowptr[node], end = rowptr[node + 1];
    float4 acc = make_float4(0.f, 0.f, 0.f, 0.f);
    int e = beg;
    for (; e + 4 <= end; e += 4) {
        int i0 = col[e + g];
        int i1 = col[e + 2 + g];
        int2 v0 = *(const int2*)(xbf + (size_t)i0 * 128 + c * 4);
        int2 v1 = *(const int2*)(xbf + (size_t)i1 * 128 + c * 4);
        addbf4(acc, v0); addbf4(acc, v1);
    }
    for (; e < end; e += 2) {
        bool valid = (e + g < end);
        int idx = valid ? col[e + g] : 0;
        int2 v = *(const int2*)(xbf + (size_t)idx * 128 + c * 4);
        if (valid) addbf4(acc, v);
    }
    acc.x += __shfl_down(acc.x, 32);
    acc.y += __shfl_down(acc.y, 32);
    acc.z += __shfl_down(acc.z, 32);
    acc.w += __shfl_down(acc.w, 32);
    if (g == 0) {
        short4 s;
        s.x = f2bf(acc.x); s.y = f2bf(acc.y); s.z = f2bf(acc.z); s.w = f2bf(acc.w);
        *(short4*)(aggbf + (size_t)node * 128 + c * 4) = s;
    }
}

// D=64: 4 groups x 16 lanes, 4 edges/issue.
__global__ __launch_bounds__(256) void gather_sum64(
    const short* __restrict__ xbf, const int* __restrict__ rowptr,
    const int* __restrict__ col, short* __restrict__ aggbf, int N)
{
    const int wave = threadIdx.x >> 6;
    const int lane = threadIdx.x & 63;
    const int node = blockIdx.x * 4 + wave;
    if (node >= N) return;
    const int g = lane >> 4;          // edge group 0..3
    const int c = lane & 15;          // int2 slot within row
    const int beg = rowptr[node], end = rowptr[node + 1];
    float4 acc = make_float4(0.f, 0.f, 0.f, 0.f);
    int e = beg;
    for (; e + 8 <= end; e += 8) {
        int i0 = col[e + g];
        int i1 = col[e + 4 + g];
        int2 v0 = *(const int2*)(xbf + (size_t)i0 * 64 + c * 4);
        int2 v1 = *(const int2*)(xbf + (size_t)i1 * 64 + c * 4);
        addbf4(acc, v0); addbf4(acc, v1);
    }
    for (; e < end; e += 4) {
        bool valid = (e + g < end);
        int idx = valid ? col[e + g] : 0;
        int2 v = *(const int2*)(xbf + (size_t)idx * 64 + c * 4);
        if (valid) addbf4(acc, v);
    }
    acc.x += __shfl_down(acc.x, 32);
    acc.y += __shfl_down(acc.y, 32);
    acc.z += __shfl_down(acc.z, 32);
    acc.w += __shfl_down(acc.w, 32);
    acc.x += __shfl_down(acc.x, 16);
    acc.y += __shfl_down(acc.y, 16);
    acc.z += __shfl_down(acc.z, 16);
    acc.w += __shfl_down(acc.w, 16);
    if (g == 0) {
        short4 s;
        s.x = f2bf(acc.x); s.y = f2bf(acc.y); s.z = f2bf(acc.z); s.w = f2bf(acc.w);
        *(short4*)(aggbf + (size_t)node * 64 + c * 4) = s;
    }
}

// ==== gather_fin128: out128 = lrelu(seg_sum(z[src]) + w + b), zw N x 256 ====
__global__ __launch_bounds__(256) void gather_fin128(
    const short* __restrict__ zw, const int* __restrict__ rowptr,
    const int* __restrict__ col, const float* __restrict__ bias,
    float* __restrict__ out, int N)
{
    const int wave = threadIdx.x >> 6;
    const int lane = threadIdx.x & 63;
    const int node = blockIdx.x * 4 + wave;
    if (node >= N) return;
    const int g = lane >> 5;
    const int c = lane & 31;
    const int beg = rowptr[node], end = rowptr[node + 1];
    float4 acc = make_float4(0.f, 0.f, 0.f, 0.f);
    if (g == 0) {   // w part + bias, added once
        int2 wv = *(const int2*)(zw + (size_t)node * 256 + 128 + c * 4);
        addbf4(acc, wv);
        float4 bb = *(const float4*)(bias + c * 4);
        acc.x += bb.x; acc.y += bb.y; acc.z += bb.z; acc.w += bb.w;
    }
    int e = beg;
    for (; e + 4 <= end; e += 4) {
        int i0 = col[e + g];
        int i1 = col[e + 2 + g];
        int2 v0 = *(const int2*)(zw + (size_t)i0 * 256 + c * 4);
        int2 v1 = *(const int2*)(zw + (size_t)i1 * 256 + c * 4);
        addbf4(acc, v0); addbf4(acc, v1);
    }
    for (; e < end; e += 2) {
        bool valid = (e + g < end);
        int idx = valid ? col[e + g] : 0;
        int2 v = *(const int2*)(zw + (size_t)idx * 256 + c * 4);
        if (valid) addbf4(acc, v);
    }
    acc.x += __shfl_down(acc.x, 32);
    acc.y += __shfl_down(acc.y, 32);
    acc.z += __shfl_down(acc.z, 32);
    acc.w += __shfl_down(acc.w, 32);
    if (g == 0) {
        acc.x = acc.x > 0.f ? acc.x : 0.01f * acc.x;
        acc.y = acc.y > 0.f ? acc.y : 0.01f * acc.y;
        acc.z = acc.z > 0.f ? acc.z : 0.01f * acc.z;
        acc.w = acc.w > 0.f ? acc.w : 0.01f * acc.w;
        *(float4*)(out + (size_t)node * 128 + c * 4) = acc;
    }
}

// ==== gather_fin64: emb = lrelu(seg_sum(z[src]) + w + b), zw N x 128 ========
__global__ __launch_bounds__(256) void gather_fin64(
    const short* __restrict__ zw, const int* __restrict__ rowptr,
    const int* __restrict__ col, const float* __restrict__ bias,
    float* __restrict__ out, short* __restrict__ out_bf, int N)
{
    const int wave = threadIdx.x >> 6;
    const int lane = threadIdx.x & 63;
    const int node = blockIdx.x * 4 + wave;
    if (node >= N) return;
    const int g = lane >> 4;
    const int c = lane & 15;
    const int beg = rowptr[node], end = rowptr[node + 1];
    float4 acc = make_float4(0.f, 0.f, 0.f, 0.f);
    if (g == 0) {
        int2 wv = *(const int2*)(zw + (size_t)node * 128 + 64 + c * 4);
        addbf4(acc, wv);
        float4 bb = *(const float4*)(bias + c * 4);
        acc.x += bb.x; acc.y += bb.y; acc.z += bb.z; acc.w += bb.w;
    }
    int e = beg;
    for (; e + 8 <= end; e += 8) {
        int i0 = col[e + g];
        int i1 = col[e + 4 + g];
        int2 v0 = *(const int2*)(zw + (size_t)i0 * 128 + c * 4);
        int2 v1 = *(const int2*)(zw + (size_t)i1 * 128 + c * 4);
        addbf4(acc, v0); addbf4(acc, v1);
    }
    for (; e < end; e += 4) {
        bool valid = (e + g < end);
        int idx = valid ? col[e + g] : 0;
        int2 v = *(const int2*)(zw + (size_t)idx * 128 + c * 4);
        if (valid) addbf4(acc, v);
    }
    acc.x += __shfl_down(acc.x, 32);
    acc.y += __shfl_down(acc.y, 32);
    acc.z += __shfl_down(acc.z, 32);
    acc.w += __shfl_down(acc.w, 32);
    acc.x += __shfl_down(acc.x, 16);
    acc.y += __shfl_down(acc.y, 16);
    acc.z += __shfl_down(acc.z, 16);
    acc.w += __shfl_down(acc.w, 16);
    if (g == 0) {
        acc.x = acc.x > 0.f ? acc.x : 0.01f * acc.x;
        acc.y = acc.y > 0.f ? acc.y : 0.01f * acc.y;
        acc.z = acc.z > 0.f ? acc.z : 0.01f * acc.z;
        acc.w = acc.w > 0.f ? acc.w : 0.01f * acc.w;
        *(float4*)(out + (size_t)node * 64 + c * 4) = acc;
        short4 s;
        s.x = f2bf(acc.x); s.y = f2bf(acc.y); s.z = f2bf(acc.z); s.w = f2bf(acc.w);
        *(short4*)(out_bf + (size_t)node * 64 + c * 4) = s;
    }
}

// ======================= MFMA GEMM (barrier-free K-loop) ====================
template<int DK, int DOUT, bool FUSED>
__global__ __launch_bounds__(256) void gemm_mfma(
    const short* __restrict__ A0, const short* __restrict__ A1,
    const short* __restrict__ B0, const short* __restrict__ B1,
    const float* __restrict__ bias, short* __restrict__ outH, int N)
{
    constexpr int KTOT  = FUSED ? 2 * DK : DK;
    constexpr int NCOLS = FUSED ? DOUT : 2 * DOUT;
    constexpr int K32   = KTOT / 32;
    constexpr int KSEG  = KTOT / 8;
    constexpr int BSH   = 128 * KTOT;
    constexpr int SMSH  = (BSH > 18432) ? BSH : 18432;

    __shared__ short smem[SMSH];
    const int tid  = threadIdx.x;
    const int row0 = blockIdx.x * 128;
    const int col0 = blockIdx.y * 128;
    const int w    = tid >> 6;
    const int lane = tid & 63;
    const int wr   = (w & 1) << 6;
    const int wc   = (w >> 1) << 6;
    const int m16  = lane & 15;
    const int quad = lane >> 4;

    #pragma unroll
    for (int it = 0; it < BSH / 8 / 256; it++) {
        int idx = tid + it * 256;
        int j = idx / KSEG;
        int t = idx % KSEG;
        int gj = col0 + j;
        const short* bp;
        int ko = t * 8;
        if (FUSED) {
            if (ko < DK) bp = B0 + (size_t)gj * DK + ko;
            else         bp = B1 + (size_t)gj * DK + (ko - DK);
        } else {
            bp = (gj < DOUT) ? (B0 + (size_t)gj * DK + ko)
                             : (B1 + (size_t)(gj - DOUT) * DK + ko);
        }
        int4 v = *(const int4*)bp;
        int kk = t >> 2, qd = t & 3, jj = j >> 4, mm = j & 15;
        *(int4*)(smem + ((((jj * K32 + kk) * 4 + qd) * 16 + mm) << 3)) = v;
    }
    __syncthreads();

    const short* arow[4];
    #pragma unroll
    for (int i = 0; i < 4; i++) {
        int r = row0 + wr + i * 16 + m16;
        r = r < N ? r : N - 1;
        arow[i] = A0 + (size_t)r * DK;
    }
    const size_t a1delta = (size_t)(A1 - A0);

    f32x4 acc[4][4] = {};
    const int jw = wc >> 4;

    #pragma unroll
    for (int kk = 0; kk < K32; kk++) {
        const int ko = kk * 32;
        bf16x8 af[4];
        #pragma unroll
        for (int i = 0; i < 4; i++) {
            const short* ap = arow[i] + (quad << 3);
            if (FUSED && ko >= DK) ap += a1delta + (ko - DK);
            else                   ap += ko;
            af[i] = *(const bf16x8*)ap;
        }
        #pragma unroll
        for (int j = 0; j < 4; j++) {
            bf16x8 bfr = *(const bf16x8*)(smem +
                (((((jw + j) * K32 + kk) * 4 + quad) * 16 + m16) << 3));
            #pragma unroll
            for (int i = 0; i < 4; i++)
                acc[i][j] = __builtin_amdgcn_mfma_f32_16x16x32_bf16(
                    af[i], bfr, acc[i][j], 0, 0, 0);
        }
    }

    __syncthreads();
    short* ep = smem + w * 4608;
    #pragma unroll
    for (int j = 0; j < 4; j++) {
        const int colg = col0 + wc + j * 16 + m16;
        const float bv = FUSED ? bias[colg] : 0.f;
        #pragma unroll
        for (int i = 0; i < 4; i++) {
            #pragma unroll
            for (int r = 0; r < 4; r++) {
                float v = acc[i][j][r];
                if (FUSED) { v += bv; v = v > 0.f ? v : 0.01f * v; }
                ep[(i * 16 + quad * 4 + r) * 72 + j * 16 + m16] = f2bf(v);
            }
        }
    }
    const int r8  = lane >> 3;
    const int seg = lane & 7;
    #pragma unroll
    for (int rb = 0; rb < 8; rb++) {
        const int lrow = rb * 8 + r8;
        int4 vv = *(const int4*)(ep + lrow * 72 + seg * 8);
        const int grow = row0 + wr + lrow;
        if (grow < N)
            *(int4*)(outH + (size_t)grow * NCOLS + col0 + wc + seg * 8) = vv;
    }
}

extern "C" void kernel_launch(void* const* d_in, const int* in_sizes, int n_in,
                              void* d_out, int out_size, void* d_ws, size_t ws_size,
                              hipStream_t stream) {
    const int N = NNODES;
    const float* x  = (const float*)d_in[0];
    const int*   ei = (const int*)d_in[1];
    const int    E  = in_sizes[1] / 2;
    const int* src = ei;
    const int* dst = ei + E;

    const float* Wr[4] = { (const float*)d_in[2], (const float*)d_in[5],
                           (const float*)d_in[8], (const float*)d_in[11] };
    const float* Ws[4] = { (const float*)d_in[3], (const float*)d_in[6],
                           (const float*)d_in[9], (const float*)d_in[12] };
    const float* bb[4] = { (const float*)d_in[4], (const float*)d_in[7],
                           (const float*)d_in[10], (const float*)d_in[13] };

    float* out  = (float*)d_out;                     // h_final: N x 128 fp32
    float* emb  = out + (size_t)N * 128;             // emb:     N x 64 fp32

    // workspace layout
    short* zwbf   = (short*)d_ws;                    // N x 256 bf16 (z|w)
    short* aggbf  = zwbf + (size_t)N * 256;          // N x 128 bf16
    short* xbf    = aggbf + (size_t)N * 128;         // N x 128 bf16
    short* h1bf   = xbf + (size_t)N * 128;           // N x 256 bf16 (also h3)
    short* embbf  = h1bf + (size_t)N * 256;          // N x 64 bf16
    short* wbf    = embbf + (size_t)N * 64;          // 196608 bf16 weights
    int*   rowptr = (int*)(wbf + 196608);            // N+1
    int*   col    = rowptr + (N + 1);                // E
    int*   coarse = col + E;                         // E
    int*   histG  = coarse + E;                      // NCB*256
    int*   btot   = histG + NCB * 256;               // NCB
    int*   bases  = btot + NCB;                      // NCB+1

    const short* wr0 = wbf;           const short* ws0 = wbf + 32768;
    const short* wr1 = wbf + 65536;   const short* ws1 = wbf + 81920;
    const short* wr2 = wbf + 98304;   const short* ws2 = wbf + 114688;
    const short* wr3 = wbf + 131072;  const short* ws3 = wbf + 163840;

    const int chunk = (E + 255) / 256;
    const int gemmRB = (N + 127) / 128;              // 391
    const int nodeBlocks = (N + 3) / 4;

    // ---- CSR build (contention-free counting sort) + converts ----
    hist_coarse<<<256, 256, 0, stream>>>(dst, histG, E, chunk);
    scan_buckets<<<NCB, 256, 0, stream>>>(histG, btot);
    scan_bases<<<1, 256, 0, stream>>>(btot, bases, E);
    scatter_coarse<<<256, 256, 0, stream>>>(src, dst, histG, bases, coarse, E, chunk);
    fill_from_coarse<<<NCB, 256, 0, stream>>>(bases, coarse, rowptr, col, N);
    cvt_x<<<(N * 128 / 4 + 255) / 256, 256, 0, stream>>>(x, xbf, N * 128 / 4);
    cvt_weights<<<(196608 + 255) / 256, 256, 0, stream>>>(
        Wr[0], Ws[0], Wr[1], Ws[1], Wr[2], Ws[2], Wr[3], Ws[3], wbf);

    // ---- Layer 0 (gather-first): 128 -> 256 ----
    gather_sum128<<<nodeBlocks, 256, 0, stream>>>(xbf, rowptr, col, aggbf, N);
    gemm_mfma<128, 256, true><<<dim3(gemmRB, 2), 256, 0, stream>>>(
        aggbf, xbf, wr0, ws0, bb[0], h1bf, N);

    // ---- Layer 1 (GEMM-first): 256 -> 64 ----
    gemm_mfma<256, 64, false><<<dim3(gemmRB, 1), 256, 0, stream>>>(
        h1bf, nullptr, wr1, ws1, nullptr, zwbf, N);            // zw1: N x 128
    gather_fin64<<<nodeBlocks, 256, 0, stream>>>(
        zwbf, rowptr, col, bb[1], emb, embbf, N);

    // ---- Layer 2 (gather-first): 64 -> 256 ----
    gather_sum64<<<nodeBlocks, 256, 0, stream>>>(embbf, rowptr, col, aggbf, N);
    gemm_mfma<64, 256, true><<<dim3(gemmRB, 2), 256, 0, stream>>>(
        aggbf, embbf, wr2, ws2, bb[2], h1bf /*h3bf*/, N);

    // ---- Layer 3 (GEMM-first): 256 -> 128 ----
    gemm_mfma<256, 128, false><<<dim3(gemmRB, 2), 256, 0, stream>>>(
        h1bf /*h3bf*/, nullptr, wr3, ws3, nullptr, zwbf, N);   // zw3: N x 256
    gather_fin128<<<nodeBlocks, 256, 0, stream>>>(
        zwbf, rowptr, col, bb[3], out, N);
}